// Round 2
// baseline (1185.472 us; speedup 1.0000x reference)
//
#include <hip/hip_runtime.h>
#include <hip/hip_bf16.h>
#include <stdint.h>

// Problem: B=4, C=64, H=W=64, L=4096.
// Outputs: y [4,64,64,64] (1048576 f32) then w [4,4096*64,3,3] (9437184 f32).
//
// Algebra: scores[(p,q),(y,x)] = sum_{a,b in -1..1} R[(p+a,q+b),(y+a,x+b)]
//          R[uv,st] = sum_c f[c,uv]*b[c,st]        (K=64 channel GEMM, exact fp32)
//          y[c,pq]  = sum_l P[pq,l]*b[c,l]         (bf16 MFMA)
//          P[pq,l]  = (1/9) sum_{a,b} attn[(pq+(a,b)), l+a*64+b]
//
// Workspace tiers (adaptive on ws_size; branch is constant across calls):
//  G4: R[4b] 256MB @0 | attn[4b] 128MB @256MB | P overlays R.        needs 384MiB
//  G1: per-batch: R 64MB @0 | attn 32MB @64MB | P overlays R.        needs 96MiB
//  ST: per-batch: attn 32MB @0 | Rstream (<=18.9MB) @32MB, then P @32MB. needs 64MiB

typedef unsigned short ushort_t;
typedef __attribute__((ext_vector_type(8))) short bf16x8;
typedef __attribute__((ext_vector_type(4))) float f32x4;

__device__ __forceinline__ float bf2f(ushort_t u){
  union { float f; uint32_t i; } v; v.i = ((uint32_t)u) << 16; return v.f;
}
__device__ __forceinline__ ushort_t f2bf(float f){
  union { float f; uint32_t i; } v; v.f = f;
  uint32_t x = v.i;
  return (ushort_t)((x + 0x7fffu + ((x >> 16) & 1u)) >> 16);  // RNE
}

// ---- k_prep: write w output (exact patch copy of b) + zero the y region ----
__global__ __launch_bounds__(256) void k_prep(const float* __restrict__ bin,
                                              float* __restrict__ wout,
                                              float* __restrict__ yzero){
  int t = blockIdx.x * 256 + threadIdx.x;        // (bb, l, c), c fastest; 1048576 total
  yzero[t] = 0.f;
  int c  = t & 63;
  int l  = (t >> 6) & 4095;
  int bb = t >> 18;
  int y = l >> 6, x = l & 63;
  const float* src = bin + (((size_t)(bb * 64 + c)) << 12);
  float* dst = wout + (size_t)t * 9;
  #pragma unroll
  for (int i = 0; i < 3; i++){
    int yy = y + i - 1;
    #pragma unroll
    for (int j = 0; j < 3; j++){
      int xx = x + j - 1;
      float v = 0.f;
      if ((unsigned)yy < 64u && (unsigned)xx < 64u) v = src[(yy << 6) + xx];
      dst[i * 3 + j] = v;
    }
  }
}

// ---- k_rgemm: R[m,n] = sum_c f[c, m_base+m] * b[c, n]  (fp32 exact) ----
// Tile 128x128, K=64 one-shot. Handles partial M via m_count mask.
__global__ __launch_bounds__(256) void k_rgemm(const float* __restrict__ f,
                                               const float* __restrict__ bin,
                                               float* __restrict__ R,
                                               int bt0, int m_base, int m_count,
                                               unsigned long long r_stride){
  __shared__ float As[64][128];
  __shared__ float Bs[64][128];
  int bt = bt0 + blockIdx.z;
  int m0 = blockIdx.x << 7;
  int n0 = blockIdx.y << 7;
  const float* fb = f   + (((size_t)bt) << 18);
  const float* bb = bin + (((size_t)bt) << 18);
  float* Rb = R + (size_t)blockIdx.z * r_stride;
  int t = threadIdx.x;
  for (int idx = t; idx < 64 * 128; idx += 256){
    int c = idx >> 7, m = idx & 127;
    As[c][m] = (m0 + m < m_count) ? fb[(c << 12) + m_base + m0 + m] : 0.f;
    Bs[c][m] = bb[(c << 12) + n0 + m];
  }
  __syncthreads();
  int tx = t & 15, ty = t >> 4;
  float acc[8][8];
  #pragma unroll
  for (int i = 0; i < 8; i++)
    #pragma unroll
    for (int j = 0; j < 8; j++) acc[i][j] = 0.f;

  for (int c = 0; c < 64; c++){
    float av[8], bv[8];
    #pragma unroll
    for (int i = 0; i < 8; i++) av[i] = As[c][(ty << 3) + i];
    #pragma unroll
    for (int j = 0; j < 4; j++) bv[j]     = Bs[c][(tx << 2) + j];
    #pragma unroll
    for (int j = 0; j < 4; j++) bv[4 + j] = Bs[c][64 + (tx << 2) + j];
    #pragma unroll
    for (int i = 0; i < 8; i++)
      #pragma unroll
      for (int j = 0; j < 8; j++) acc[i][j] += av[i] * bv[j];
  }
  #pragma unroll
  for (int i = 0; i < 8; i++){
    int mrow = m0 + (ty << 3) + i;
    if (mrow < m_count){
      float* dst = Rb + ((size_t)mrow << 12) + n0;
      *(float4*)(dst + (tx << 2))      = make_float4(acc[i][0], acc[i][1], acc[i][2], acc[i][3]);
      *(float4*)(dst + 64 + (tx << 2)) = make_float4(acc[i][4], acc[i][5], acc[i][6], acc[i][7]);
    }
  }
}

// ---- k_softmax: S = 10 * 9-tap diagonal stencil of R; softmax over l; attn bf16 ----
// One wg per query row (p,q); 256 threads x 16 = 4096 keys.
__global__ __launch_bounds__(256) void k_softmax(const float* __restrict__ R,
                                                 ushort_t* __restrict__ attn,
                                                 int p_base, int m_base,
                                                 unsigned long long r_stride,
                                                 unsigned long long a_stride){
  int row = (p_base << 6) + blockIdx.x;   // global pq
  int p = row >> 6, q = row & 63;
  const float* Rz = R + (size_t)blockIdx.y * r_stride;
  int t = threadIdx.x;
  float s[16];
  #pragma unroll
  for (int k = 0; k < 16; k++) s[k] = 0.f;

  #pragma unroll
  for (int a = -1; a <= 1; a++){
    if ((unsigned)(p + a) >= 64u) continue;
    #pragma unroll
    for (int b2 = -1; b2 <= 1; b2++){
      if ((unsigned)(q + b2) >= 64u) continue;
      const float* Rrow = Rz + ((size_t)(((p + a) << 6) + (q + b2) - m_base) << 12);
      int shift = a * 64 + b2;
      #pragma unroll
      for (int k = 0; k < 16; k++){
        int l = (k << 8) + t;
        int y = l >> 6, x = l & 63;
        if ((unsigned)(y + a) < 64u && (unsigned)(x + b2) < 64u)
          s[k] += Rrow[l + shift];
      }
    }
  }
  float m = -1e30f;
  #pragma unroll
  for (int k = 0; k < 16; k++){ s[k] *= 10.f; m = fmaxf(m, s[k]); }
  #pragma unroll
  for (int off = 32; off; off >>= 1) m = fmaxf(m, __shfl_xor(m, off));
  __shared__ float redm[4];
  __shared__ float reds[4];
  int wv = t >> 6;
  if ((t & 63) == 0) redm[wv] = m;
  __syncthreads();
  m = fmaxf(fmaxf(redm[0], redm[1]), fmaxf(redm[2], redm[3]));

  float e[16]; float sum = 0.f;
  #pragma unroll
  for (int k = 0; k < 16; k++){ e[k] = __expf(s[k] - m); sum += e[k]; }
  #pragma unroll
  for (int off = 32; off; off >>= 1) sum += __shfl_xor(sum, off);
  if ((t & 63) == 0) reds[wv] = sum;
  __syncthreads();
  sum = reds[0] + reds[1] + reds[2] + reds[3];
  float inv = 1.0f / sum;

  ushort_t* arow = attn + (size_t)blockIdx.y * a_stride + ((size_t)row << 12);
  #pragma unroll
  for (int k = 0; k < 16; k++) arow[(k << 8) + t] = f2bf(e[k] * inv);
}

// ---- k_pstencil: P = (1/9) * same 9-tap stencil applied to attn (bf16 in/out) ----
__global__ __launch_bounds__(256) void k_pstencil(const ushort_t* __restrict__ attn,
                                                  ushort_t* __restrict__ P,
                                                  unsigned long long a_stride,
                                                  unsigned long long p_stride){
  int row = blockIdx.x;
  int p = row >> 6, q = row & 63;
  const ushort_t* az = attn + (size_t)blockIdx.y * a_stride;
  int t = threadIdx.x;
  float s[16];
  #pragma unroll
  for (int k = 0; k < 16; k++) s[k] = 0.f;

  #pragma unroll
  for (int a = -1; a <= 1; a++){
    if ((unsigned)(p + a) >= 64u) continue;
    #pragma unroll
    for (int b2 = -1; b2 <= 1; b2++){
      if ((unsigned)(q + b2) >= 64u) continue;
      const ushort_t* arow = az + ((size_t)(((p + a) << 6) + (q + b2)) << 12);
      int shift = a * 64 + b2;
      #pragma unroll
      for (int k = 0; k < 16; k++){
        int l = (k << 8) + t;
        int y = l >> 6, x = l & 63;
        if ((unsigned)(y + a) < 64u && (unsigned)(x + b2) < 64u)
          s[k] += bf2f(arow[l + shift]);
      }
    }
  }
  ushort_t* prow = P + (size_t)blockIdx.y * p_stride + ((size_t)row << 12);
  const float inv9 = 1.0f / 9.0f;
  #pragma unroll
  for (int k = 0; k < 16; k++) prow[(k << 8) + t] = f2bf(s[k] * inv9);
}

// ---- k_ygemm: y[c,pq] = sum_l P[pq,l]*b[c,l]; 16x16x32 bf16 MFMA; K-split 4 + atomics ----
__global__ __launch_bounds__(256) void k_ygemm(const float* __restrict__ bin,
                                               const ushort_t* __restrict__ P,
                                               float* __restrict__ y,
                                               int bt0, unsigned long long p_stride){
  __shared__ ushort_t SB[64][72];   // SB[c][k]   (72*2=144B rows: 16B-aligned)
  __shared__ ushort_t SP[64][72];   // SP[pq][k]
  int bt  = bt0 + blockIdx.z;
  int pq0 = blockIdx.x << 6;
  int k0  = blockIdx.y << 10;
  int t = threadIdx.x;
  int lane = t & 63, wv = t >> 6;
  const float*    bbase = bin + (((size_t)bt) << 18);
  const ushort_t* Pbase = P + (size_t)blockIdx.z * p_stride + ((size_t)pq0 << 12);

  f32x4 acc[4];
  #pragma unroll
  for (int cb = 0; cb < 4; cb++) acc[cb] = (f32x4){0.f, 0.f, 0.f, 0.f};

  for (int kb = k0; kb < k0 + 1024; kb += 64){
    for (int idx = t; idx < 1024; idx += 256){
      int c = idx >> 4, g = idx & 15;
      float4 v = *(const float4*)(bbase + (c << 12) + kb + (g << 2));
      ushort_t* d = &SB[c][g << 2];
      d[0] = f2bf(v.x); d[1] = f2bf(v.y); d[2] = f2bf(v.z); d[3] = f2bf(v.w);
    }
    for (int idx = t; idx < 1024; idx += 256){
      int r = idx >> 4, g = idx & 15;
      *(uint64_t*)&SP[r][g << 2] =
          *(const uint64_t*)(Pbase + (((size_t)r) << 12) + kb + (g << 2));
    }
    __syncthreads();
    #pragma unroll
    for (int ks = 0; ks < 64; ks += 32){
      bf16x8 pf = *(const bf16x8*)&SP[(wv << 4) + (lane & 15)][ks + ((lane >> 4) << 3)];
      #pragma unroll
      for (int cb = 0; cb < 4; cb++){
        bf16x8 bf = *(const bf16x8*)&SB[(cb << 4) + (lane & 15)][ks + ((lane >> 4) << 3)];
        acc[cb] = __builtin_amdgcn_mfma_f32_16x16x32_bf16(bf, pf, acc[cb], 0, 0, 0);
      }
    }
    __syncthreads();
  }
  int quad = lane >> 4;
  int pql = pq0 + (wv << 4) + (lane & 15);
  #pragma unroll
  for (int cb = 0; cb < 4; cb++)
    #pragma unroll
    for (int r = 0; r < 4; r++){
      int c = (cb << 4) + (quad << 2) + r;
      atomicAdd(&y[(((size_t)(bt * 64 + c)) << 12) + pql], acc[cb][r]);
    }
}

extern "C" void kernel_launch(void* const* d_in, const int* in_sizes, int n_in,
                              void* d_out, int out_size, void* d_ws, size_t ws_size,
                              hipStream_t stream){
  const float* f = (const float*)d_in[0];
  const float* b = (const float*)d_in[1];
  float* out  = (float*)d_out;
  float* yout = out;
  float* wout = out + 1048576;

  const size_t RB = 4096ull * 4096 * 4;   // 64 MiB (fp32 R per batch)
  const size_t AB = 4096ull * 4096 * 2;   // 32 MiB (bf16 attn/P per batch)

  k_prep<<<4096, 256, 0, stream>>>(b, wout, yout);   // also zeroes y

  if (ws_size >= 4 * (RB + AB)) {
    // All 4 batches at once.
    float*    R    = (float*)d_ws;
    ushort_t* attn = (ushort_t*)((char*)d_ws + 4 * RB);
    ushort_t* P    = (ushort_t*)d_ws;                // overlays R (dead after softmax)
    k_rgemm   <<<dim3(32, 32, 4), 256, 0, stream>>>(f, b, R, 0, 0, 4096, RB / 4);
    k_softmax <<<dim3(4096, 4),   256, 0, stream>>>(R, attn, 0, 0, RB / 4, AB / 2);
    k_pstencil<<<dim3(4096, 4),   256, 0, stream>>>(attn, P, AB / 2, AB / 2);
    k_ygemm   <<<dim3(64, 4, 4),  256, 0, stream>>>(b, P, yout, 0, AB / 2);
  } else if (ws_size >= RB + AB) {
    // One batch at a time: R 64MB | attn 32MB; P overlays R.
    float*    R    = (float*)d_ws;
    ushort_t* attn = (ushort_t*)((char*)d_ws + RB);
    ushort_t* P    = (ushort_t*)d_ws;
    for (int bt = 0; bt < 4; bt++){
      k_rgemm   <<<dim3(32, 32, 1), 256, 0, stream>>>(f, b, R, bt, 0, 4096, 0);
      k_softmax <<<dim3(4096, 1),   256, 0, stream>>>(R, attn, 0, 0, 0, 0);
      k_pstencil<<<dim3(4096, 1),   256, 0, stream>>>(attn, P, 0, 0);
      k_ygemm   <<<dim3(64, 4, 1),  256, 0, stream>>>(b, P, yout, bt, 0);
    }
  } else {
    // Streamed: attn 32MB @0; R stream blocks (<=18.9MB) then P @32MB. Floor 64MiB.
    ushort_t* attn = (ushort_t*)d_ws;
    float*    R    = (float*)((char*)d_ws + AB);
    ushort_t* P    = (ushort_t*)((char*)d_ws + AB);
    for (int bt = 0; bt < 4; bt++){
      for (int p0 = 0; p0 < 64; p0 += 16){
        int lo = (p0 > 0) ? p0 - 1 : 0;
        int hi = (p0 + 16 < 64) ? p0 + 16 : 63;
        int m_base = lo << 6, m_count = (hi - lo + 1) << 6;   // 1088 or 1152
        k_rgemm  <<<dim3((m_count + 127) >> 7, 32, 1), 256, 0, stream>>>(
                      f, b, R, bt, m_base, m_count, 0);
        k_softmax<<<dim3(1024, 1), 256, 0, stream>>>(R, attn, p0, m_base, 0, 0);
      }
      k_pstencil<<<dim3(4096, 1), 256, 0, stream>>>(attn, P, 0, 0);
      k_ygemm   <<<dim3(64, 4, 1), 256, 0, stream>>>(b, P, yout, bt, 0);
    }
  }
}

// Round 3
// 858.538 us; speedup vs baseline: 1.3808x; 1.3808x over previous
//
#include <hip/hip_runtime.h>
#include <hip/hip_bf16.h>
#include <hip/hip_fp16.h>
#include <stdint.h>

// Problem: B=4, C=64, H=W=64, L=4096.
// Outputs: y [4,64,64,64] (1048576 f32) then w [4,4096*64,3,3] (9437184 f32).
//
// Algebra: scores[(p,q),(y,x)] = sum_{a,b in -1..1} R[(p+a,q+b),(y+a,x+b)]
//          R[uv,st] = sum_c f[c,uv]*b[c,st]        (K=64 channel GEMM, exact fp32)
//          y[c,pq]  = sum_l P[pq,l]*b[c,l]         (bf16 MFMA)
//          P[pq,l]  = (1/9) sum_{a,b} attn[(pq+(a,b)), l+a*64+b]
//
// Workspace (G1 tier, per-batch loop): R 64MB @0 | attn 32MB @64MB; P overlays R.
// ST fallback tier for ws < 96 MiB uses the simple (round-2) kernels.

typedef unsigned short ushort_t;
typedef __attribute__((ext_vector_type(8))) short bf16x8;
typedef __attribute__((ext_vector_type(4))) float f32x4;

__device__ __forceinline__ float bf2f(ushort_t u){
  union { float f; uint32_t i; } v; v.i = ((uint32_t)u) << 16; return v.f;
}
__device__ __forceinline__ ushort_t f2bf(float f){
  union { float f; uint32_t i; } v; v.f = f;
  uint32_t x = v.i;
  return (ushort_t)((x + 0x7fffu + ((x >> 16) & 1u)) >> 16);  // RNE
}

// ---- k_prep: write w output (exact patch copy of b) + zero the y region ----
__global__ __launch_bounds__(256) void k_prep(const float* __restrict__ bin,
                                              float* __restrict__ wout,
                                              float* __restrict__ yzero){
  int t = blockIdx.x * 256 + threadIdx.x;        // (bb, l, c), c fastest; 1048576 total
  yzero[t] = 0.f;
  int c  = t & 63;
  int l  = (t >> 6) & 4095;
  int bb = t >> 18;
  int y = l >> 6, x = l & 63;
  const float* src = bin + (((size_t)(bb * 64 + c)) << 12);
  float* dst = wout + (size_t)t * 9;
  #pragma unroll
  for (int i = 0; i < 3; i++){
    int yy = y + i - 1;
    #pragma unroll
    for (int j = 0; j < 3; j++){
      int xx = x + j - 1;
      float v = 0.f;
      if ((unsigned)yy < 64u && (unsigned)xx < 64u) v = src[(yy << 6) + xx];
      dst[i * 3 + j] = v;
    }
  }
}

// ---- k_rgemm: R[m,n] = sum_c f[c, m_base+m] * b[c, n]  (fp32 exact) ----
__global__ __launch_bounds__(256) void k_rgemm(const float* __restrict__ f,
                                               const float* __restrict__ bin,
                                               float* __restrict__ R,
                                               int bt0, int m_base, int m_count,
                                               unsigned long long r_stride){
  __shared__ float As[64][128];
  __shared__ float Bs[64][128];
  int bt = bt0 + blockIdx.z;
  int m0 = blockIdx.x << 7;
  int n0 = blockIdx.y << 7;
  const float* fb = f   + (((size_t)bt) << 18);
  const float* bb = bin + (((size_t)bt) << 18);
  float* Rb = R + (size_t)blockIdx.z * r_stride;
  int t = threadIdx.x;
  for (int idx = t; idx < 64 * 128; idx += 256){
    int c = idx >> 7, m = idx & 127;
    As[c][m] = (m0 + m < m_count) ? fb[(c << 12) + m_base + m0 + m] : 0.f;
    Bs[c][m] = bb[(c << 12) + n0 + m];
  }
  __syncthreads();
  int tx = t & 15, ty = t >> 4;
  float acc[8][8];
  #pragma unroll
  for (int i = 0; i < 8; i++)
    #pragma unroll
    for (int j = 0; j < 8; j++) acc[i][j] = 0.f;

  for (int c = 0; c < 64; c++){
    float av[8], bv[8];
    #pragma unroll
    for (int i = 0; i < 8; i++) av[i] = As[c][(ty << 3) + i];
    #pragma unroll
    for (int j = 0; j < 4; j++) bv[j]     = Bs[c][(tx << 2) + j];
    #pragma unroll
    for (int j = 0; j < 4; j++) bv[4 + j] = Bs[c][64 + (tx << 2) + j];
    #pragma unroll
    for (int i = 0; i < 8; i++)
      #pragma unroll
      for (int j = 0; j < 8; j++) acc[i][j] += av[i] * bv[j];
  }
  #pragma unroll
  for (int i = 0; i < 8; i++){
    int mrow = m0 + (ty << 3) + i;
    if (mrow < m_count){
      float* dst = Rb + ((size_t)mrow << 12) + n0;
      *(float4*)(dst + (tx << 2))      = make_float4(acc[i][0], acc[i][1], acc[i][2], acc[i][3]);
      *(float4*)(dst + 64 + (tx << 2)) = make_float4(acc[i][4], acc[i][5], acc[i][6], acc[i][7]);
    }
  }
}

// =====================================================================
// k_softmax3: fused single-pass stencil+softmax.
// WG = 4x2 query tile (8 queries, 32 key-threads each). Per 512-key chunk:
// stage 24 R rows (+-68 halo) into LDS, 9-tap stencil from LDS, online
// softmax per thread; store s - mref(c) as fp16 in LDS (64KB); epilogue
// merges (m,l) over 32 lanes and writes bf16 attn. R fetched once.
// LDS = 62208 + 65536 = 127744 B -> 1 WG/CU (gfx950: 160KB/WG).
// =====================================================================
__global__ __launch_bounds__(256) void k_softmax3(const float* __restrict__ R,
                                                  ushort_t* __restrict__ attn){
  __shared__ float  Rt[24][648];
  __shared__ __half Sh[8][4096];
  const int t  = threadIdx.x;
  const int bb = blockIdx.x;
  const int inner = bb >> 3;
  const int ty = ((bb & 7) << 1) | (inner & 1);   // XCD band swizzle: XCD k -> p-band
  const int tx = inner >> 1;
  const int p0 = ty << 2, q0 = tx << 1;
  const int qi = t >> 5, kt = t & 31;
  const int pi = qi >> 1, qj = qi & 1;
  const int ktx = kt & 15;

  float M = -3.0e38f, L = 0.f;
  float mref[8];
  float4 rbuf[16];

  // prefetch chunk 0 staging into registers
  {
    #pragma unroll
    for (int i = 0; i < 16; i++){
      int idx = t + (i << 8);
      float4 v = make_float4(0.f, 0.f, 0.f, 0.f);
      if (idx < 3888){
        unsigned r = (unsigned)idx / 162u;
        int fo = idx - (int)r * 162;
        int rp = p0 - 1 + (int)(r >> 2);
        int rq = q0 - 1 + (int)(r & 3);
        int kg = -68 + (fo << 2);
        if ((unsigned)rp < 64u && (unsigned)rq < 64u && (unsigned)kg <= 4092u)
          v = *(const float4*)(R + (((size_t)((rp << 6) + rq)) << 12) + kg);
      }
      rbuf[i] = v;
    }
  }

  for (int c = 0; c < 8; c++){
    __syncthreads();
    #pragma unroll
    for (int i = 0; i < 16; i++){
      int idx = t + (i << 8);
      if (idx < 3888) ((float4*)&Rt[0][0])[idx] = rbuf[i];
    }
    __syncthreads();
    if (c < 7){
      const int k0 = (c + 1) << 9;
      #pragma unroll
      for (int i = 0; i < 16; i++){
        int idx = t + (i << 8);
        float4 v = make_float4(0.f, 0.f, 0.f, 0.f);
        if (idx < 3888){
          unsigned r = (unsigned)idx / 162u;
          int fo = idx - (int)r * 162;
          int rp = p0 - 1 + (int)(r >> 2);
          int rq = q0 - 1 + (int)(r & 3);
          int kg = k0 - 68 + (fo << 2);
          if ((unsigned)rp < 64u && (unsigned)rq < 64u && (unsigned)kg <= 4092u)
            v = *(const float4*)(R + (((size_t)((rp << 6) + rq)) << 12) + kg);
        }
        rbuf[i] = v;
      }
    }
    // 9-tap stencil from LDS for this thread's 16 keys
    float4 sv[4];
    #pragma unroll
    for (int j = 0; j < 4; j++){
      int y = (c << 3) + (j << 1) + (kt >> 4);
      int sa0 = (j << 7) + (kt << 2) + 68;
      float4 s = make_float4(0.f, 0.f, 0.f, 0.f);
      #pragma unroll
      for (int a = -1; a <= 1; a++){
        if ((unsigned)(y + a) < 64u){
          int rb = (pi + 1 + a) << 2;
          int sa = sa0 + (a << 6);
          const float* r0 = Rt[rb + qj];       // b=-1 row (zero-filled if OOB)
          const float* r1 = Rt[rb + qj + 1];   // b=0
          const float* r2 = Rt[rb + qj + 2];   // b=+1
          float4 A0 = *(const float4*)&r0[sa];
          float  Lv = r0[sa - 1];
          float4 A1 = *(const float4*)&r1[sa];
          float4 A2 = *(const float4*)&r2[sa];
          float  Rv = r2[sa + 4];
          s.x += (ktx == 0 ? 0.f : Lv) + A1.x + A2.y;
          s.y += A0.x + A1.y + A2.z;
          s.z += A0.y + A1.z + A2.w;
          s.w += A0.z + A1.w + (ktx == 15 ? 0.f : Rv);
        }
      }
      s.x *= 10.f; s.y *= 10.f; s.z *= 10.f; s.w *= 10.f;
      sv[j] = s;
    }
    // online softmax update over this chunk's 16 values
    float mc = M;
    #pragma unroll
    for (int j = 0; j < 4; j++)
      mc = fmaxf(mc, fmaxf(fmaxf(sv[j].x, sv[j].y), fmaxf(sv[j].z, sv[j].w)));
    float lnew = L * __expf(M - mc);
    #pragma unroll
    for (int j = 0; j < 4; j++)
      lnew += __expf(sv[j].x - mc) + __expf(sv[j].y - mc)
            + __expf(sv[j].z - mc) + __expf(sv[j].w - mc);
    L = lnew; M = mc; mref[c] = mc;
    #pragma unroll
    for (int j = 0; j < 4; j++){
      __half* shp = &Sh[qi][(c << 9) + (j << 7) + (kt << 2)];
      shp[0] = __float2half(fmaxf(sv[j].x - mc, -16.f));
      shp[1] = __float2half(fmaxf(sv[j].y - mc, -16.f));
      shp[2] = __float2half(fmaxf(sv[j].z - mc, -16.f));
      shp[3] = __float2half(fmaxf(sv[j].w - mc, -16.f));
    }
  }
  // merge (M,L) across the 32 lanes of this query
  #pragma unroll
  for (int off = 1; off < 32; off <<= 1){
    float m2 = __shfl_xor(M, off);
    float l2 = __shfl_xor(L, off);
    float mn = fmaxf(M, m2);
    L = L * __expf(M - mn) + l2 * __expf(m2 - mn);
    M = mn;
  }
  float invL = 1.0f / L;
  int row = ((p0 + pi) << 6) + q0 + qj;
  ushort_t* arow = attn + ((size_t)row << 12);
  #pragma unroll
  for (int c = 0; c < 8; c++){
    float d = mref[c] - M;
    #pragma unroll
    for (int j = 0; j < 4; j++){
      const __half* shp = &Sh[qi][(c << 9) + (j << 7) + (kt << 2)];
      ushort4 o;
      o.x = f2bf(__expf(__half2float(shp[0]) + d) * invL);
      o.y = f2bf(__expf(__half2float(shp[1]) + d) * invL);
      o.z = f2bf(__expf(__half2float(shp[2]) + d) * invL);
      o.w = f2bf(__expf(__half2float(shp[3]) + d) * invL);
      *(ushort4*)&arow[(c << 9) + (j << 7) + (kt << 2)] = o;
    }
  }
}

// =====================================================================
// k_pstencil3: LDS-tiled single-pass P = (1/9)*stencil9(attn). Same 4x2
// tiling/swizzle as k_softmax3; attn staged bf16->fp32 into LDS (62KB,
// 2 WG/CU), taps from LDS, bf16 P out.
// =====================================================================
__global__ __launch_bounds__(256) void k_pstencil3(const ushort_t* __restrict__ attn,
                                                   ushort_t* __restrict__ P){
  __shared__ float At[24][648];
  const int t  = threadIdx.x;
  const int bb = blockIdx.x;
  const int inner = bb >> 3;
  const int ty = ((bb & 7) << 1) | (inner & 1);
  const int tx = inner >> 1;
  const int p0 = ty << 2, q0 = tx << 1;
  const int qi = t >> 5, kt = t & 31;
  const int pi = qi >> 1, qj = qi & 1;
  const int ktx = kt & 15;

  int row = ((p0 + pi) << 6) + q0 + qj;
  ushort_t* prow = P + ((size_t)row << 12);
  const float inv9 = 1.0f / 9.0f;

  ushort4 rbuf[16];
  {
    #pragma unroll
    for (int i = 0; i < 16; i++){
      int idx = t + (i << 8);
      ushort4 v; v.x = 0; v.y = 0; v.z = 0; v.w = 0;
      if (idx < 3888){
        unsigned r = (unsigned)idx / 162u;
        int fo = idx - (int)r * 162;
        int rp = p0 - 1 + (int)(r >> 2);
        int rq = q0 - 1 + (int)(r & 3);
        int kg = -68 + (fo << 2);
        if ((unsigned)rp < 64u && (unsigned)rq < 64u && (unsigned)kg <= 4092u)
          v = *(const ushort4*)(attn + (((size_t)((rp << 6) + rq)) << 12) + kg);
      }
      rbuf[i] = v;
    }
  }

  for (int c = 0; c < 8; c++){
    __syncthreads();
    #pragma unroll
    for (int i = 0; i < 16; i++){
      int idx = t + (i << 8);
      if (idx < 3888)
        ((float4*)&At[0][0])[idx] =
            make_float4(bf2f(rbuf[i].x), bf2f(rbuf[i].y), bf2f(rbuf[i].z), bf2f(rbuf[i].w));
    }
    __syncthreads();
    if (c < 7){
      const int k0 = (c + 1) << 9;
      #pragma unroll
      for (int i = 0; i < 16; i++){
        int idx = t + (i << 8);
        ushort4 v; v.x = 0; v.y = 0; v.z = 0; v.w = 0;
        if (idx < 3888){
          unsigned r = (unsigned)idx / 162u;
          int fo = idx - (int)r * 162;
          int rp = p0 - 1 + (int)(r >> 2);
          int rq = q0 - 1 + (int)(r & 3);
          int kg = k0 - 68 + (fo << 2);
          if ((unsigned)rp < 64u && (unsigned)rq < 64u && (unsigned)kg <= 4092u)
            v = *(const ushort4*)(attn + (((size_t)((rp << 6) + rq)) << 12) + kg);
        }
        rbuf[i] = v;
      }
    }
    #pragma unroll
    for (int j = 0; j < 4; j++){
      int y = (c << 3) + (j << 1) + (kt >> 4);
      int sa0 = (j << 7) + (kt << 2) + 68;
      float4 s = make_float4(0.f, 0.f, 0.f, 0.f);
      #pragma unroll
      for (int a = -1; a <= 1; a++){
        if ((unsigned)(y + a) < 64u){
          int rb = (pi + 1 + a) << 2;
          int sa = sa0 + (a << 6);
          const float* r0 = At[rb + qj];
          const float* r1 = At[rb + qj + 1];
          const float* r2 = At[rb + qj + 2];
          float4 A0 = *(const float4*)&r0[sa];
          float  Lv = r0[sa - 1];
          float4 A1 = *(const float4*)&r1[sa];
          float4 A2 = *(const float4*)&r2[sa];
          float  Rv = r2[sa + 4];
          s.x += (ktx == 0 ? 0.f : Lv) + A1.x + A2.y;
          s.y += A0.x + A1.y + A2.z;
          s.z += A0.y + A1.z + A2.w;
          s.w += A0.z + A1.w + (ktx == 15 ? 0.f : Rv);
        }
      }
      ushort4 o;
      o.x = f2bf(s.x * inv9);
      o.y = f2bf(s.y * inv9);
      o.z = f2bf(s.z * inv9);
      o.w = f2bf(s.w * inv9);
      *(ushort4*)&prow[(c << 9) + (j << 7) + (kt << 2)] = o;
    }
  }
}

// ---- old simple kernels kept for the ST (small-ws) fallback tier ----
__global__ __launch_bounds__(256) void k_softmax(const float* __restrict__ R,
                                                 ushort_t* __restrict__ attn,
                                                 int p_base, int m_base,
                                                 unsigned long long r_stride,
                                                 unsigned long long a_stride){
  int row = (p_base << 6) + blockIdx.x;
  int p = row >> 6, q = row & 63;
  const float* Rz = R + (size_t)blockIdx.y * r_stride;
  int t = threadIdx.x;
  float s[16];
  #pragma unroll
  for (int k = 0; k < 16; k++) s[k] = 0.f;
  #pragma unroll
  for (int a = -1; a <= 1; a++){
    if ((unsigned)(p + a) >= 64u) continue;
    #pragma unroll
    for (int b2 = -1; b2 <= 1; b2++){
      if ((unsigned)(q + b2) >= 64u) continue;
      const float* Rrow = Rz + ((size_t)(((p + a) << 6) + (q + b2) - m_base) << 12);
      int shift = a * 64 + b2;
      #pragma unroll
      for (int k = 0; k < 16; k++){
        int l = (k << 8) + t;
        int y = l >> 6, x = l & 63;
        if ((unsigned)(y + a) < 64u && (unsigned)(x + b2) < 64u)
          s[k] += Rrow[l + shift];
      }
    }
  }
  float m = -1e30f;
  #pragma unroll
  for (int k = 0; k < 16; k++){ s[k] *= 10.f; m = fmaxf(m, s[k]); }
  #pragma unroll
  for (int off = 32; off; off >>= 1) m = fmaxf(m, __shfl_xor(m, off));
  __shared__ float redm[4];
  __shared__ float reds[4];
  int wv = t >> 6;
  if ((t & 63) == 0) redm[wv] = m;
  __syncthreads();
  m = fmaxf(fmaxf(redm[0], redm[1]), fmaxf(redm[2], redm[3]));
  float e[16]; float sum = 0.f;
  #pragma unroll
  for (int k = 0; k < 16; k++){ e[k] = __expf(s[k] - m); sum += e[k]; }
  #pragma unroll
  for (int off = 32; off; off >>= 1) sum += __shfl_xor(sum, off);
  if ((t & 63) == 0) reds[wv] = sum;
  __syncthreads();
  sum = reds[0] + reds[1] + reds[2] + reds[3];
  float inv = 1.0f / sum;
  ushort_t* arow = attn + (size_t)blockIdx.y * a_stride + ((size_t)row << 12);
  #pragma unroll
  for (int k = 0; k < 16; k++) arow[(k << 8) + t] = f2bf(e[k] * inv);
}

__global__ __launch_bounds__(256) void k_pstencil(const ushort_t* __restrict__ attn,
                                                  ushort_t* __restrict__ P,
                                                  unsigned long long a_stride,
                                                  unsigned long long p_stride){
  int row = blockIdx.x;
  int p = row >> 6, q = row & 63;
  const ushort_t* az = attn + (size_t)blockIdx.y * a_stride;
  int t = threadIdx.x;
  float s[16];
  #pragma unroll
  for (int k = 0; k < 16; k++) s[k] = 0.f;
  #pragma unroll
  for (int a = -1; a <= 1; a++){
    if ((unsigned)(p + a) >= 64u) continue;
    #pragma unroll
    for (int b2 = -1; b2 <= 1; b2++){
      if ((unsigned)(q + b2) >= 64u) continue;
      const ushort_t* arow = az + ((size_t)(((p + a) << 6) + (q + b2)) << 12);
      int shift = a * 64 + b2;
      #pragma unroll
      for (int k = 0; k < 16; k++){
        int l = (k << 8) + t;
        int y = l >> 6, x = l & 63;
        if ((unsigned)(y + a) < 64u && (unsigned)(x + b2) < 64u)
          s[k] += bf2f(arow[l + shift]);
      }
    }
  }
  ushort_t* prow = P + (size_t)blockIdx.y * p_stride + ((size_t)row << 12);
  const float inv9 = 1.0f / 9.0f;
  #pragma unroll
  for (int k = 0; k < 16; k++) prow[(k << 8) + t] = f2bf(s[k] * inv9);
}

// ---- k_ygemm: y[c,pq] = sum_l P[pq,l]*b[c,l]; 16x16x32 bf16 MFMA; K-split 4 + atomics ----
__global__ __launch_bounds__(256) void k_ygemm(const float* __restrict__ bin,
                                               const ushort_t* __restrict__ P,
                                               float* __restrict__ y,
                                               int bt0, unsigned long long p_stride){
  __shared__ ushort_t SB[64][72];
  __shared__ ushort_t SP[64][72];
  int bt  = bt0 + blockIdx.z;
  int pq0 = blockIdx.x << 6;
  int k0  = blockIdx.y << 10;
  int t = threadIdx.x;
  int lane = t & 63, wv = t >> 6;
  const float*    bbase = bin + (((size_t)bt) << 18);
  const ushort_t* Pbase = P + (size_t)blockIdx.z * p_stride + ((size_t)pq0 << 12);

  f32x4 acc[4];
  #pragma unroll
  for (int cb = 0; cb < 4; cb++) acc[cb] = (f32x4){0.f, 0.f, 0.f, 0.f};

  for (int kb = k0; kb < k0 + 1024; kb += 64){
    for (int idx = t; idx < 1024; idx += 256){
      int c = idx >> 4, g = idx & 15;
      float4 v = *(const float4*)(bbase + (c << 12) + kb + (g << 2));
      ushort_t* d = &SB[c][g << 2];
      d[0] = f2bf(v.x); d[1] = f2bf(v.y); d[2] = f2bf(v.z); d[3] = f2bf(v.w);
    }
    for (int idx = t; idx < 1024; idx += 256){
      int r = idx >> 4, g = idx & 15;
      *(uint64_t*)&SP[r][g << 2] =
          *(const uint64_t*)(Pbase + (((size_t)r) << 12) + kb + (g << 2));
    }
    __syncthreads();
    #pragma unroll
    for (int ks = 0; ks < 64; ks += 32){
      bf16x8 pf = *(const bf16x8*)&SP[(wv << 4) + (lane & 15)][ks + ((lane >> 4) << 3)];
      #pragma unroll
      for (int cb = 0; cb < 4; cb++){
        bf16x8 bf = *(const bf16x8*)&SB[(cb << 4) + (lane & 15)][ks + ((lane >> 4) << 3)];
        acc[cb] = __builtin_amdgcn_mfma_f32_16x16x32_bf16(bf, pf, acc[cb], 0, 0, 0);
      }
    }
    __syncthreads();
  }
  int quad = lane >> 4;
  int pql = pq0 + (wv << 4) + (lane & 15);
  #pragma unroll
  for (int cb = 0; cb < 4; cb++)
    #pragma unroll
    for (int r = 0; r < 4; r++){
      int c = (cb << 4) + (quad << 2) + r;
      atomicAdd(&y[(((size_t)(bt * 64 + c)) << 12) + pql], acc[cb][r]);
    }
}

extern "C" void kernel_launch(void* const* d_in, const int* in_sizes, int n_in,
                              void* d_out, int out_size, void* d_ws, size_t ws_size,
                              hipStream_t stream){
  const float* f = (const float*)d_in[0];
  const float* b = (const float*)d_in[1];
  float* out  = (float*)d_out;
  float* yout = out;
  float* wout = out + 1048576;

  const size_t RB = 4096ull * 4096 * 4;   // 64 MiB fp32 R per batch
  const size_t AB = 4096ull * 4096 * 2;   // 32 MiB bf16 attn/P per batch

  k_prep<<<4096, 256, 0, stream>>>(b, wout, yout);   // also zeroes y

  if (ws_size >= RB + AB) {
    // G1: one batch at a time. R @0 | attn @64MB; P overlays R.
    float*    R    = (float*)d_ws;
    ushort_t* attn = (ushort_t*)((char*)d_ws + RB);
    ushort_t* P    = (ushort_t*)d_ws;
    for (int bt = 0; bt < 4; bt++){
      const float* fb = f + (((size_t)bt) << 18);
      const float* bbp = b + (((size_t)bt) << 18);
      (void)fb; (void)bbp;
      k_rgemm    <<<dim3(32, 32, 1), 256, 0, stream>>>(f, b, R, bt, 0, 4096, 0);
      k_softmax3 <<<512, 256, 0, stream>>>(R, attn);
      k_pstencil3<<<512, 256, 0, stream>>>(attn, P);
      k_ygemm    <<<dim3(64, 4, 1), 256, 0, stream>>>(b, P, yout, bt, 0);
    }
  } else {
    // ST fallback: attn 32MB @0; R stream blocks then P @32MB. Floor 64MiB.
    ushort_t* attn = (ushort_t*)d_ws;
    float*    R    = (float*)((char*)d_ws + AB);
    ushort_t* P    = (ushort_t*)((char*)d_ws + AB);
    for (int bt = 0; bt < 4; bt++){
      for (int p0 = 0; p0 < 64; p0 += 16){
        int lo = (p0 > 0) ? p0 - 1 : 0;
        int hi = (p0 + 16 < 64) ? p0 + 16 : 63;
        int m_base = lo << 6, m_count = (hi - lo + 1) << 6;
        k_rgemm  <<<dim3((m_count + 127) >> 7, 32, 1), 256, 0, stream>>>(
                      f, b, R, bt, m_base, m_count, 0);
        k_softmax<<<dim3(1024, 1), 256, 0, stream>>>(R, attn, p0 >> 0, m_base, 0, 0);
      }
      k_pstencil<<<dim3(4096, 1), 256, 0, stream>>>(attn, P, 0, 0);
      k_ygemm   <<<dim3(64, 4, 1), 256, 0, stream>>>(b, P, yout, bt, 0);
    }
  }
}